// Round 2
// baseline (7736.466 us; speedup 1.0000x reference)
//
#include <hip/hip_runtime.h>
#include <stdint.h>

// LSTM: B=256, T=1024, I=64, H=256, O=1. fp32 in/out, bf16 MFMA internally.
//
// Round-13 = Round-11 (verified best, 2223us) + same-XCD fast path done with
// L2-POINT ATOMICS (R12's sc0 plain-load/store fast path FAILED: plain ops
// depend on L1 policy - sc0 loads may hit a stale L1 line and sc0 stores may
// linger in L1; dead-latched polls then consumed ~2-step-stale h, absmax
// 0.114). Atomics are never serviced by L1: an atomic WITHOUT sc1 executes
// at the local XCD L2 (sc0 on atomics = return-old flag only). So:
//   consumer poll  = global_atomic_add_x2(+0) sc0  -> fresh read at XCD L2
//   producer pub   = global_atomic_swap_x2 (no ret)-> 8B atomic into XCD L2
// Per-address total order at the L2 keeps the tag protocol untouched.
//
// Placement is NOT assumed (G16): group g's 8 slice-blocks are bid=g+32s
// (bid%8==g%8 -> same XCD under round-robin), verified at runtime by an
// XCC_ID consensus handshake through parity-0 slots gbase+0..7 (HTAG-tagged,
// agent scope). All 8 blocks see identical data -> all-or-nothing per group.
// Split groups keep the verified R11 agent (MALL) path.
//
// Final-h handoff: RMW polling dirties parity lines in XCD L2s; an agent
// store to those SAME addresses could later be clobbered by the dirty-line
// writeback. So tag-1024 h goes to a SEPARATE region (offset 2*UPP) that no
// L2 atomic ever touches, via agent stores (MALL authoritative, clean
// lines); lstm_fc reads it with agent loads. No consumer polls tag 1024.
//
// Handshake safety: slots gbase+0..7 (parity 0) are dead until end of step
// 1; their tag-2 overwrite (L2 swap) is causally after all peers' handshake
// reads (peer publishes tag 1 only after its handshake completed; tag-2
// writer saw all tag-1 units). Cross-run staleness: stale tags (<=1024,
// 0xAAAAAAAA, HTAG) are overwritten monotonically (tags 2,4,..) long before
// any poll expects them. Quiet poll (R8/R10: hot polling congests fabric):
// first check before any sleep, s_sleep(1) between sweeps, satisfied lanes
// stop issuing. Dead-latch caps => wrong-answer-not-hang.
//
// Structure (R3/R9/R11 proven): 256 blocks = 32 batch-groups (8 batches) x
// 8 gate-slices (128 gate rows). Weights register-resident as bf16 MFMA
// B-fragments. h published as 8B single-copy-atomic units {2xbf16 h, tag}.

#define T_ 1024
#define I_ 64
#define H_ 256
#define NSLICE 8
#define NGROUP 32
#define MB 8      /* batches per group  */
#define HB 32     /* hidden units per block */
#define HROW 272  /* padded h_lds row (ushorts), 544 B = 34 x 16 B */

#define UNITS_PER_GROUP 1024                       /* 8B units per step */
#define UNITS_PER_PARITY (NGROUP * UNITS_PER_GROUP)
#define SENT_CAP (1 << 16)   /* dead-latch: ~64k sleep-sweeps */
#define HTAG 0x48414E44u     /* "HAND": != live tags 1..1024, != 0xAAAAAAAA */
#define HS_CAP (1 << 20)     /* handshake sweep cap: never trips */

typedef float floatx4 __attribute__((ext_vector_type(4)));
typedef __bf16 bf16x8 __attribute__((ext_vector_type(8)));
typedef unsigned short ushortx8 __attribute__((ext_vector_type(8)));
typedef unsigned int uintx4 __attribute__((ext_vector_type(4)));
typedef unsigned int uint32;
typedef unsigned long long u64;

__device__ __forceinline__ float bf2f(uint32 u16) {
  uint32 u = u16 << 16;
  return __builtin_bit_cast(float, u);
}
__device__ __forceinline__ bf16x8 packbf8(floatx4 a, floatx4 b) {
  bf16x8 r;
  r[0] = (__bf16)a[0]; r[1] = (__bf16)a[1];
  r[2] = (__bf16)a[2]; r[3] = (__bf16)a[3];
  r[4] = (__bf16)b[0]; r[5] = (__bf16)b[1];
  r[6] = (__bf16)b[2]; r[7] = (__bf16)b[3];
  return r;
}
__device__ __forceinline__ float fast_sig(float v) {
  return 1.0f / (1.0f + __expf(-v));
}
__device__ __forceinline__ float fast_tanh(float v) {
  float e = __expf(2.0f * v);
  return 1.0f - 2.0f / (e + 1.0f);
}
__device__ __forceinline__ u64 aload64(const u64* p) {
  return __hip_atomic_load(p, __ATOMIC_RELAXED, __HIP_MEMORY_SCOPE_AGENT);
}
// ---- same-XCD fast path primitives: L2-point atomics (L1 never involved).
// add_x2 with +0 and sc0 (=return old) is a fresh read at the XCD L2.
__device__ __forceinline__ void poll4_l2(u64* p, u64& a, u64& b, u64& c,
                                         u64& d) {
  const u64 z = 0;
  asm volatile(
      "global_atomic_add_x2 %0, %4, %5, off sc0\n\t"
      "global_atomic_add_x2 %1, %4, %5, off offset:8 sc0\n\t"
      "global_atomic_add_x2 %2, %4, %5, off offset:16 sc0\n\t"
      "global_atomic_add_x2 %3, %4, %5, off offset:24 sc0\n\t"
      "s_waitcnt vmcnt(0)"
      : "=&v"(a), "=&v"(b), "=&v"(c), "=&v"(d)
      : "v"(p), "v"(z)
      : "memory");
}
__device__ __forceinline__ void publish_l2(u64* p, u64 v) {
  asm volatile("global_atomic_swap_x2 %0, %1, off" ::"v"(p), "v"(v)
               : "memory");
}
__device__ __forceinline__ void load4_agent(const u64* p, u64& a, u64& b,
                                            u64& c, u64& d) {
  a = aload64(p + 0);
  b = aload64(p + 1);
  c = aload64(p + 2);
  d = aload64(p + 3);
}
__device__ __forceinline__ bool tags_ok(u64 v0, u64 v1, u64 v2, u64 v3,
                                        int t) {
  return ((uint32)(v0 >> 32) == (uint32)t) &
         ((uint32)(v1 >> 32) == (uint32)t) &
         ((uint32)(v2 >> 32) == (uint32)t) &
         ((uint32)(v3 >> 32) == (uint32)t);
}
__device__ __forceinline__ int xcc_id() {
  int x;
  asm volatile("s_getreg_b32 %0, hwreg(HW_REG_XCC_ID)" : "=s"(x));
  return x & 0xf;
}

__global__ __launch_bounds__(256, 1) void lstm_main(
    const float* __restrict__ x, const float* __restrict__ W_ih,
    const float* __restrict__ W_hh, const float* __restrict__ b_ih,
    const float* __restrict__ b_hh, u64* __restrict__ units) {
  const int tid = threadIdx.x;
  const int bid = blockIdx.x;
  const int s = bid >> 5;     // slice 0..7  (bid%8 == g%8 -> group on 1 XCD)
  const int g = bid & 31;     // group 0..31
  const int w = tid >> 6;     // wave id == gate type (i,f,g,o)
  const int lane = tid & 63;
  const int ln = lane & 15;   // MFMA n / A m
  const int lk = lane >> 4;   // MFMA k-subgroup (8 elems each)

  __shared__ float xch[4][2][16][8];                     // [gate][j][n][m]
  __shared__ __align__(16) unsigned short h_lds[MB][HROW];

  const size_t gbase = (size_t)g * UNITS_PER_GROUP;

  // ---- publish my XCD id ASAP (agent scope -> MALL) ----
  if (tid == 0) {
    u64 hv = (u64)(uint32)xcc_id() | ((u64)HTAG << 32);
    __hip_atomic_store(units + gbase + s, hv, __ATOMIC_RELAXED,
                       __HIP_MEMORY_SCOPE_AGENT);
  }

  // zero h_lds (h_0 = 0 for t=0; also clears pad)
  {
    uint32* p = (uint32*)&h_lds[0][0];
    for (int i = tid; i < MB * HROW / 2; i += 256) p[i] = 0u;
  }

  // ---- preload weight B-fragments (bf16) + bias, once ----
  bf16x8 wf[2][10];
  float bias[2];
#pragma unroll
  for (int j = 0; j < 2; ++j) {
    const int row = w * 256 + s * HB + j * 16 + ln;
    bias[j] = b_ih[row] + b_hh[row];
#pragma unroll
    for (int kc = 0; kc < 10; ++kc) {
      const int kk = kc * 32 + lk * 8;
      const float* src = (kk < I_) ? (W_ih + (size_t)row * I_ + kk)
                                   : (W_hh + (size_t)row * H_ + (kk - I_));
      floatx4 f0 = *(const floatx4*)src;
      floatx4 f1 = *(const floatx4*)(src + 4);
      wf[j][kc] = packbf8(f0, f1);
    }
  }

  // ---- XCD consensus: fast iff all 8 slices of the group share one XCD.
  // All threads poll the 8 once-written slots -> identical decision.
  bool fast;
  {
    u64 idv[8] = {0, 0, 0, 0, 0, 0, 0, 0};
    bool hok = false;
    for (int it = 0; !hok && it < HS_CAP; ++it) {
      hok = true;
#pragma unroll
      for (int p = 0; p < 8; ++p) {
        idv[p] = aload64(units + gbase + p);
        hok &= ((uint32)(idv[p] >> 32) == HTAG);
      }
      if (!hok) __builtin_amdgcn_s_sleep(2);
    }
    fast = hok;
#pragma unroll
    for (int p = 1; p < 8; ++p) fast &= ((uint32)idv[0] == (uint32)idv[p]);
  }

  const int mb = ln & 7;                       // batch row (m>=8 duplicates)
  const float* xrow = x + ((size_t)(g * MB + mb)) * T_ * I_;
  // update-phase roles
  const int um = tid >> 5;                     // 0..7 batch
  const int uh = tid & 31;                     // 0..31 hidden local
  const int uj = uh >> 4, un = uh & 15;
  float c_reg = 0.0f;

  __syncthreads();

#pragma unroll 1
  for (int t = 0; t < T_; ++t) {
    // x loads issued first so they overlap the poll
    floatx4 xf0, xf1, xf2, xf3;
    {
      const float* src = xrow + t * I_ + lk * 8;
      xf0 = *(const floatx4*)(src);
      xf1 = *(const floatx4*)(src + 4);
      xf2 = *(const floatx4*)(src + 32);
      xf3 = *(const floatx4*)(src + 36);
    }

    if (t > 0) {
      u64* up = units + (size_t)(t & 1) * UNITS_PER_PARITY + gbase + tid * 4;
      // ---- single-phase quiet poll: all 4 units per sweep, sleep backoff.
      // Payload captured in the detecting sweep. Fast path reads the shared
      // per-XCD L2 via atomic(+0); slow path reads MALL (agent load).
      u64 v0, v1, v2, v3;
      if (fast) poll4_l2(up, v0, v1, v2, v3);
      else      load4_agent(up, v0, v1, v2, v3);
      bool ok = tags_ok(v0, v1, v2, v3, t);
      int it = 0;
      while (!__all(ok) && ++it < SENT_CAP) {
        __builtin_amdgcn_s_sleep(1);
        if (!ok) {
          if (fast) poll4_l2(up, v0, v1, v2, v3);
          else      load4_agent(up, v0, v1, v2, v3);
          ok = tags_ok(v0, v1, v2, v3, t);
        }
      }
      uintx4 d;
      d[0] = (uint32)v0; d[1] = (uint32)v1;
      d[2] = (uint32)v2; d[3] = (uint32)v3;
      // unit u = m*128 + dword; tid*4 = (tid>>5)*128 + (tid&31)*4
      uint32* dst = (uint32*)&h_lds[tid >> 5][0] + (tid & 31) * 4;
      *(uintx4*)dst = d;  // 16B aligned
    }
    __syncthreads();  // S1: h_lds ready

    bf16x8 af[10];
    af[0] = packbf8(xf0, xf1);
    af[1] = packbf8(xf2, xf3);
    const unsigned short* hrow = &h_lds[mb][0];
#pragma unroll
    for (int kc = 2; kc < 10; ++kc) {
      af[kc] =
          __builtin_bit_cast(bf16x8, *(const ushortx8*)(hrow + (kc - 2) * 32 +
                                                        lk * 8));
    }

    // ---- MFMA: D[m][n] = sum_k A[m][k] * W[n][k], bias in acc ----
    floatx4 acc[2];
    acc[0] = (floatx4){bias[0], bias[0], bias[0], bias[0]};
    acc[1] = (floatx4){bias[1], bias[1], bias[1], bias[1]};
#pragma unroll
    for (int kc = 0; kc < 10; ++kc) {
      acc[0] = __builtin_amdgcn_mfma_f32_16x16x32_bf16(af[kc], wf[0][kc],
                                                       acc[0], 0, 0, 0);
      acc[1] = __builtin_amdgcn_mfma_f32_16x16x32_bf16(af[kc], wf[1][kc],
                                                       acc[1], 0, 0, 0);
    }

    // ---- nonlinearity (wave-uniform branch) + LDS exchange ----
#pragma unroll
    for (int j = 0; j < 2; ++j) {
      floatx4 v = acc[j];
      if (w == 2) {
        v[0] = fast_tanh(v[0]); v[1] = fast_tanh(v[1]);
        v[2] = fast_tanh(v[2]); v[3] = fast_tanh(v[3]);
      } else {
        v[0] = fast_sig(v[0]); v[1] = fast_sig(v[1]);
        v[2] = fast_sig(v[2]); v[3] = fast_sig(v[3]);
      }
      if (lk < 2) {  // valid m rows 0..7 live in lanes 0..31, m = lk*4+reg
        *(floatx4*)&xch[w][j][ln][lk * 4] = v;
      }
    }
    __syncthreads();  // S2: gates ready

    // ---- c/h update: thread = (um, uh) ----
    float ig = xch[0][uj][un][um];
    float fg = xch[1][uj][un][um];
    float gg = xch[2][uj][un][um];
    float og = xch[3][uj][un][um];
    c_reg = fg * c_reg + ig * gg;
    float hv = og * fast_tanh(c_reg);

    // pair-pack via shfl, publish 8B unit {h pair, tag t+1}
    unsigned short hb = __builtin_bit_cast(unsigned short, (__bf16)hv);
    int pv = __shfl_xor((int)hb, 1);
    if ((uh & 1) == 0) {
      uint32 dword = (uint32)hb | ((uint32)(unsigned short)pv << 16);
      u64 val = (u64)dword | ((u64)(uint32)(t + 1) << 32);
      const size_t uoff = gbase + (um * 128 + s * 16 + (uh >> 1));
      if (t == T_ - 1) {
        // final h -> separate clean region (never RMW'd => no dirty-line
        // clobber; MALL authoritative; no flush dependency). No consumer
        // polls tag 1024.
        __hip_atomic_store(units + 2 * (size_t)UNITS_PER_PARITY + uoff, val,
                           __ATOMIC_RELAXED, __HIP_MEMORY_SCOPE_AGENT);
      } else {
        u64* dst = units + (size_t)((t + 1) & 1) * UNITS_PER_PARITY + uoff;
        if (fast) {
          publish_l2(dst, val);  // 8B atomic into shared XCD L2
        } else {
          __hip_atomic_store(dst, val, __ATOMIC_RELAXED,
                             __HIP_MEMORY_SCOPE_AGENT);
        }
      }
    }
  }
}

// out[b] = dot(h_T[b], fc_w) + fc_b. Final h lives in the clean region at
// offset 2*UPP (agent-stored at end of step 1023). Agent loads bypass all
// caches -> fresh across replays, no dependence on end-of-dispatch L2 flush.
__global__ void lstm_fc(const u64* __restrict__ units,
                        const float* __restrict__ fc_w,
                        const float* __restrict__ fc_b,
                        float* __restrict__ out) {
  const int b = threadIdx.x;
  const int g = b >> 3, m = b & 7;
  const u64* base =
      units + 2 * (size_t)UNITS_PER_PARITY + (size_t)g * UNITS_PER_GROUP +
      m * 128;
  float sum = fc_b[0];
#pragma unroll 8
  for (int d = 0; d < 128; ++d) {
    u64 v = aload64(base + d);
    uint32 lo = (uint32)v;
    sum += bf2f(lo & 0xffffu) * fc_w[2 * d] + bf2f(lo >> 16) * fc_w[2 * d + 1];
  }
  out[b] = sum;
}

extern "C" void kernel_launch(void* const* d_in, const int* in_sizes, int n_in,
                              void* d_out, int out_size, void* d_ws,
                              size_t ws_size, hipStream_t stream) {
  const float* x    = (const float*)d_in[0];
  const float* W_ih = (const float*)d_in[1];
  const float* W_hh = (const float*)d_in[2];
  const float* b_ih = (const float*)d_in[3];
  const float* b_hh = (const float*)d_in[4];
  const float* fc_w = (const float*)d_in[5];
  const float* fc_b = (const float*)d_in[6];
  float* out = (float*)d_out;

  u64* units = (u64*)d_ws;  // 2 parities + final region: 3*256KB = 768KB ws
  // tag poison 0xAAAAAAAA != any live tag (1..1024) => no init needed.
  // Handshake transiently borrows parity-0 slots gbase+0..7 (HTAG-tagged;
  // dead until end of step 1, overwrite ordered after all peers' handshake).

  lstm_main<<<dim3(NGROUP * NSLICE), dim3(256), 0, stream>>>(
      x, W_ih, W_hh, b_ih, b_hh, units);
  lstm_fc<<<dim3(1), dim3(256), 0, stream>>>(units, fc_w, fc_b, out);
}

// Round 3
// 2747.788 us; speedup vs baseline: 2.8155x; 2.8155x over previous
//
#include <hip/hip_runtime.h>
#include <stdint.h>

// LSTM: B=256, T=1024, I=64, H=256, O=1. fp32 in/out, bf16 MFMA internally.
//
// Round-14: topology change. R13's counters (WRITE_SIZE 9.68GB, FETCH 40MB,
// HBM 16%) prove the workload is fabric-latency bound and that atomic RMW
// polling is ruinous; R12 proved sc0 plain ops are incoherent. So all
// communication is back to the R11-verified primitive: relaxed AGENT-scope
// (MALL) loads/stores. The lever is topology: merge each group's 8x256
// blocks into 4x512 blocks (8 waves). Per-wave work is IDENTICAL to R11
// (same wf[2][10] fragments, same 20 MFMAs, same A-fragments); a block now
// covers 64 hidden units (quarter of H) for its 8 batches.
//   - own quarter of h is written straight into LDS after the update phase
//     (zero fabric on the self-dependency)
//   - poll covers only 3 peer quarters (6KB vs 8KB), and 128 blocks instead
//     of 256 -> MALL read traffic 2MB -> 768KB/step, fewer agents, less
//     jitter
//   - pipelined quiet poll: retry loads are issued BEFORE s_sleep(1) so
//     ~900cy MALL latency hides under the sleep. Sleep-gating kept (R8/R10:
//     hot polling congests the fabric); first check before any sleep;
//     payload captured in the detecting sweep; satisfied lanes stop
//     issuing; SENT_CAP dead-latch => wrong-answer-not-hang.
//
// Parity-reuse safety (R11 argument, re-derived for quarters): tag-t units
// are overwritten (tag t+2, same parity) only at end of step t+1, which
// requires the writer's poll(t+1), which requires every peer's tag-(t+1)
// publish, which happens only after that peer's poll(t) completed. Tag
// poison 0xAAAAAAAA never equals live tags 1..1024 => no ws init needed.
//
// Final-h handoff: tag-1024 h goes to a separate clean region (offset
// 2*UPP, R13-verified) via agent stores; lstm_fc reads it with agent loads.
// No consumer polls tag 1024.
//
// Layout: 128 blocks = 32 groups x 4 quarters. Unit (8B, single-copy
// atomic) = {2xbf16 h pair, tag=step}: index g*1024 + q*256 + m*32 + p,
// pair p covers hidden q*64+2p, q*64+2p+1 of batch g*8+m.

#define T_ 1024
#define I_ 64
#define H_ 256
#define NQUAD 4
#define NGROUP 32
#define MB 8      /* batches per group  */
#define QH 64     /* hidden units per block (quarter) */
#define HROW 272  /* padded h_lds row (ushorts), 544 B = 34 x 16 B */

#define UNITS_PER_GROUP 1024                       /* 8B units per step */
#define UNITS_PER_PARITY (NGROUP * UNITS_PER_GROUP)
#define SENT_CAP (1 << 16)   /* dead-latch: ~64k sleep-sweeps */

typedef float floatx4 __attribute__((ext_vector_type(4)));
typedef __bf16 bf16x8 __attribute__((ext_vector_type(8)));
typedef unsigned short ushortx8 __attribute__((ext_vector_type(8)));
typedef unsigned int uint32;
typedef unsigned long long u64;

__device__ __forceinline__ float bf2f(uint32 u16) {
  uint32 u = u16 << 16;
  return __builtin_bit_cast(float, u);
}
__device__ __forceinline__ bf16x8 packbf8(floatx4 a, floatx4 b) {
  bf16x8 r;
  r[0] = (__bf16)a[0]; r[1] = (__bf16)a[1];
  r[2] = (__bf16)a[2]; r[3] = (__bf16)a[3];
  r[4] = (__bf16)b[0]; r[5] = (__bf16)b[1];
  r[6] = (__bf16)b[2]; r[7] = (__bf16)b[3];
  return r;
}
__device__ __forceinline__ float fast_sig(float v) {
  return 1.0f / (1.0f + __expf(-v));
}
__device__ __forceinline__ float fast_tanh(float v) {
  float e = __expf(2.0f * v);
  return 1.0f - 2.0f / (e + 1.0f);
}
__device__ __forceinline__ u64 aload64(const u64* p) {
  return __hip_atomic_load(p, __ATOMIC_RELAXED, __HIP_MEMORY_SCOPE_AGENT);
}

__global__ __launch_bounds__(512, 1) void lstm_main(
    const float* __restrict__ x, const float* __restrict__ W_ih,
    const float* __restrict__ W_hh, const float* __restrict__ b_ih,
    const float* __restrict__ b_hh, u64* __restrict__ units) {
  const int tid = threadIdx.x;
  const int bid = blockIdx.x;
  const int q = bid >> 5;     // quarter 0..3
  const int g = bid & 31;     // group 0..31 (bid%8 spreads XCDs)
  const int w8 = tid >> 6;    // wave 0..7
  const int gate = w8 & 3;    // i,f,g,o
  const int ss = w8 >> 2;     // subslice 0..1 within quarter
  const int lane = tid & 63;
  const int ln = lane & 15;   // MFMA n / C col
  const int lk = lane >> 4;   // MFMA k-subgroup (8 elems each)

  __shared__ float xch[4][2][2][16][8];              // [gate][ss][j][n][m]
  __shared__ __align__(16) unsigned short h_lds[MB][HROW];
  unsigned short* const hflat = &h_lds[0][0];

  const size_t gbase = (size_t)g * UNITS_PER_GROUP;

  // zero h_lds (h_0 = 0 for t=0; also clears pad)
  {
    uint32* p = (uint32*)hflat;
    for (int i = tid; i < MB * HROW / 2; i += 512) p[i] = 0u;
  }

  // ---- preload weight B-fragments (bf16) + bias, once ----
  // rows: gate*256 + q*64 + ss*32 + j*16 + ln  (1024 rows over 4 blocks)
  bf16x8 wf[2][10];
  float bias[2];
#pragma unroll
  for (int j = 0; j < 2; ++j) {
    const int row = gate * 256 + q * QH + ss * 32 + j * 16 + ln;
    bias[j] = b_ih[row] + b_hh[row];
#pragma unroll
    for (int kc = 0; kc < 10; ++kc) {
      const int kk = kc * 32 + lk * 8;
      const float* src = (kk < I_) ? (W_ih + (size_t)row * I_ + kk)
                                   : (W_hh + (size_t)row * H_ + (kk - I_));
      floatx4 f0 = *(const floatx4*)src;
      floatx4 f1 = *(const floatx4*)(src + 4);
      wf[j][kc] = packbf8(f0, f1);
    }
  }

  // ---- poll role precompute: 768 peer units, thread i -> unit i, and
  // threads 0..255 also unit 512+i. Peer quarter list pq[k]=k+(k>=q).
  const bool two = (tid < 256);                  // wave-uniform (waves 0-3)
  const int k0 = tid >> 8;                       // 0..1
  const int qq0 = k0 + (k0 >= q ? 1 : 0);
  const int idx0 = tid & 255;
  const int qq1 = 2 + (2 >= q ? 1 : 0);          // pq[2]
  const int idx1 = tid;                          // valid when two
  const size_t uoff0 = gbase + (size_t)(qq0 * 256 + idx0);
  const size_t uoff1 = gbase + (size_t)(qq1 * 256 + idx1);
  const int ldsoff0 = (idx0 >> 5) * HROW + qq0 * QH + (idx0 & 31) * 2;
  const int ldsoff1 = (idx1 >> 5) * HROW + qq1 * QH + (idx1 & 31) * 2;

  const int mb = ln & 7;                       // batch row (m>=8 duplicates)
  const float* xrow = x + ((size_t)(g * MB + mb)) * T_ * I_;
  // update-phase roles: thread = (um 0..7 batch, uhl 0..63 hidden-local)
  const int um = tid >> 6;
  const int uhl = tid & 63;
  const int ssu = uhl >> 5, u5 = uhl & 31;
  const int uj = u5 >> 4, un = u5 & 15;
  float c_reg = 0.0f;

  __syncthreads();

#pragma unroll 1
  for (int t = 0; t < T_; ++t) {
    // x loads issued first so they overlap the poll
    floatx4 xf0, xf1, xf2, xf3;
    {
      const float* src = xrow + t * I_ + lk * 8;
      xf0 = *(const floatx4*)(src);
      xf1 = *(const floatx4*)(src + 4);
      xf2 = *(const floatx4*)(src + 32);
      xf3 = *(const floatx4*)(src + 36);
    }

    if (t > 0) {
      const u64* up0 = units + (size_t)(t & 1) * UNITS_PER_PARITY + uoff0;
      const u64* up1 = units + (size_t)(t & 1) * UNITS_PER_PARITY + uoff1;
      // ---- pipelined quiet poll: first probe immediately; on retry,
      // issue loads BEFORE the sleep so MALL latency hides under it.
      u64 v0 = aload64(up0);
      u64 v1 = 0;
      if (two) v1 = aload64(up1);
      bool ok = ((uint32)(v0 >> 32) == (uint32)t);
      if (two) ok &= ((uint32)(v1 >> 32) == (uint32)t);
      int it = 0;
      while (!__all(ok) && ++it < SENT_CAP) {
        u64 n0 = 0, n1 = 0;
        if (!ok) {
          n0 = aload64(up0);
          if (two) n1 = aload64(up1);
        }
        __builtin_amdgcn_s_sleep(1);
        if (!ok) {
          v0 = n0; v1 = n1;
          ok = ((uint32)(v0 >> 32) == (uint32)t);
          if (two) ok &= ((uint32)(v1 >> 32) == (uint32)t);
        }
      }
      // capture payload (detecting sweep's own values) into h_lds
      *(uint32*)&hflat[ldsoff0] = (uint32)v0;
      if (two) *(uint32*)&hflat[ldsoff1] = (uint32)v1;
    }
    __syncthreads();  // S1: h_lds ready (peer quarters + own from last step)

    bf16x8 af[10];
    af[0] = packbf8(xf0, xf1);
    af[1] = packbf8(xf2, xf3);
    const unsigned short* hrow = &h_lds[mb][0];
#pragma unroll
    for (int kc = 2; kc < 10; ++kc) {
      af[kc] =
          __builtin_bit_cast(bf16x8, *(const ushortx8*)(hrow + (kc - 2) * 32 +
                                                        lk * 8));
    }

    // ---- MFMA: D[m][n] = sum_k A[m][k] * W[n][k], bias in acc ----
    floatx4 acc[2];
    acc[0] = (floatx4){bias[0], bias[0], bias[0], bias[0]};
    acc[1] = (floatx4){bias[1], bias[1], bias[1], bias[1]};
#pragma unroll
    for (int kc = 0; kc < 10; ++kc) {
      acc[0] = __builtin_amdgcn_mfma_f32_16x16x32_bf16(af[kc], wf[0][kc],
                                                       acc[0], 0, 0, 0);
      acc[1] = __builtin_amdgcn_mfma_f32_16x16x32_bf16(af[kc], wf[1][kc],
                                                       acc[1], 0, 0, 0);
    }

    // ---- nonlinearity (wave-uniform branch) + LDS exchange ----
#pragma unroll
    for (int j = 0; j < 2; ++j) {
      floatx4 v = acc[j];
      if (gate == 2) {
        v[0] = fast_tanh(v[0]); v[1] = fast_tanh(v[1]);
        v[2] = fast_tanh(v[2]); v[3] = fast_tanh(v[3]);
      } else {
        v[0] = fast_sig(v[0]); v[1] = fast_sig(v[1]);
        v[2] = fast_sig(v[2]); v[3] = fast_sig(v[3]);
      }
      if (lk < 2) {  // valid m rows 0..7 live in lanes 0..31, m = lk*4+reg
        *(floatx4*)&xch[gate][ss][j][ln][lk * 4] = v;
      }
    }
    __syncthreads();  // S2: gates ready

    // ---- c/h update: thread = (um, uhl); hidden global = q*64 + uhl ----
    float ig = xch[0][ssu][uj][un][um];
    float fg = xch[1][ssu][uj][un][um];
    float gg = xch[2][ssu][uj][un][um];
    float og = xch[3][ssu][uj][un][um];
    c_reg = fg * c_reg + ig * gg;
    float hv = og * fast_tanh(c_reg);

    // pair-pack via shfl; even thread owns pair (uhl, uhl+1)
    unsigned short hb = __builtin_bit_cast(unsigned short, (__bf16)hv);
    int pv = __shfl_xor((int)hb, 1);
    if ((tid & 1) == 0) {
      uint32 dword = (uint32)hb | ((uint32)(unsigned short)pv << 16);
      // own quarter -> straight into LDS for next step (no fabric)
      *(uint32*)&hflat[um * HROW + q * QH + uhl] = dword;
      u64 val = (u64)dword | ((u64)(uint32)(t + 1) << 32);
      const size_t uoff = gbase + (size_t)(q * 256 + um * 32 + (uhl >> 1));
      if (t == T_ - 1) {
        // final h -> separate clean region (R13-verified handoff)
        __hip_atomic_store(units + 2 * (size_t)UNITS_PER_PARITY + uoff, val,
                           __ATOMIC_RELAXED, __HIP_MEMORY_SCOPE_AGENT);
      } else {
        __hip_atomic_store(units + (size_t)((t + 1) & 1) * UNITS_PER_PARITY +
                               uoff,
                           val, __ATOMIC_RELAXED, __HIP_MEMORY_SCOPE_AGENT);
      }
    }
  }
}

// out[b] = dot(h_T[b], fc_w) + fc_b. Final h lives in the clean region at
// offset 2*UPP. Agent loads -> fresh across replays, no flush dependency.
__global__ void lstm_fc(const u64* __restrict__ units,
                        const float* __restrict__ fc_w,
                        const float* __restrict__ fc_b,
                        float* __restrict__ out) {
  const int b = threadIdx.x;
  const int g = b >> 3, m = b & 7;
  const u64* base =
      units + 2 * (size_t)UNITS_PER_PARITY + (size_t)g * UNITS_PER_GROUP;
  float sum = fc_b[0];
#pragma unroll 8
  for (int u = 0; u < 128; ++u) {
    const int qq = u >> 5, p = u & 31;
    u64 v = aload64(base + qq * 256 + m * 32 + p);
    uint32 lo = (uint32)v;
    const int d = qq * QH + 2 * p;
    sum += bf2f(lo & 0xffffu) * fc_w[d] + bf2f(lo >> 16) * fc_w[d + 1];
  }
  out[b] = sum;
}

extern "C" void kernel_launch(void* const* d_in, const int* in_sizes, int n_in,
                              void* d_out, int out_size, void* d_ws,
                              size_t ws_size, hipStream_t stream) {
  const float* x    = (const float*)d_in[0];
  const float* W_ih = (const float*)d_in[1];
  const float* W_hh = (const float*)d_in[2];
  const float* b_ih = (const float*)d_in[3];
  const float* b_hh = (const float*)d_in[4];
  const float* fc_w = (const float*)d_in[5];
  const float* fc_b = (const float*)d_in[6];
  float* out = (float*)d_out;

  u64* units = (u64*)d_ws;  // 2 parities + final region: 3*256KB = 768KB ws
  // tag poison 0xAAAAAAAA != any live tag (1..1024) => no init needed.

  lstm_main<<<dim3(NGROUP * NQUAD), dim3(512), 0, stream>>>(
      x, W_ih, W_hh, b_ih, b_hh, units);
  lstm_fc<<<dim3(1), dim3(256), 0, stream>>>(units, fc_w, fc_b, out);
}